// Round 9
// baseline (464.138 us; speedup 1.0000x reference)
//
#include <hip/hip_runtime.h>
#include <cstdint>
#include <cstddef>

// PureCartesianTensorProduct: B=4096, C1=C2=COUT=64, LMAX=2, FEAT=832, 15 paths.
// out[z,c,m] = sum_p sum_ab W_p[c,a,b] * T_p,m[z,a,b].   MFMA f32_32x32x16_f16.
//
// R9: exploit path multiplicity + kill all scattered loads.
// R0-R8 invariant (24-25% MfmaUtil across 5 structures) decomposed: at full
// MFMA rate the kernel saturates TA line-requests (W: 8 req/MFMA; staging
// scatter: ~7K lines/chunk at d2=9) while VALU sits at ~0.8 cap and only 2
// acc dep-chains/wave. R5's FETCH=106MB proves W was already L2-hit (the
// "L3-stream" theory of R3/R8 was wrong).
// Fixes:
//  * Slot-triples share W: slots 1-3 use paths {1,3,6,7,10,14}, 4-6/7-9/10-12
//    use {2,4,8,9,11,12}. Block = 12 waves = zg(2) x aq(2) x m(3): the 3
//    m-waves read the IDENTICAL W stream -> L1 dedup (3x fewer unique bytes),
//    and the XCD-pair grid mapping gives each XCD a ~3MB L2-resident W set.
//  * One-time transpose pre-kernel: X1T[s][a][z], X2T[s][z][b] f16 planes.
//    x2 tile staged ONCE per block into LDS X2L[13][64][72] (117 KB,
//    coalesced, bank-rotate stride 72) -> x2 fragments are clean ds_read_b128.
//    x1 scalars read from X1T global: 32 contiguous f16 = ONE line per load
//    (R6's poison was 32 lines/load), prefetched 2 a-steps ahead.
//  * ZERO per-chunk barriers: after one staging barrier waves run fully async.
//  * Single-buffered af W prefetch -> ~145 VGPR, fits 3 waves/SIMD (<=170).
// Slot 0 (no m-sharing): 64 tail blocks, waves take chunk-subsets.
// Epilogue: aq/m partials via one LDS exchange (Dv aliases X2L).

#define FEAT 832

typedef _Float16 half8 __attribute__((ext_vector_type(8)));
typedef float floatx16 __attribute__((ext_vector_type(16)));

struct Chunk {
  int wbase;               // p * 262144 into swizzled f16 W
  int s1[3];               // x1 plane index per term
  int s2[3];               // x2 plane index per term
  unsigned short sgm[3];   // f16 sign mask (0 or 0x8000)
  int nt;
};

// Swizzle W f32 [p][c][k] -> f16 A-frag order (unchanged, proven):
// Wsw[((p*256+ksg)*2+cgrp)*512 + lane*8+j] = W_p[cgrp*32+(lane&31)][ksg*16+(lane>>5)*8+j]
__global__ void swz_w_kernel(const float* __restrict__ w, _Float16* __restrict__ o) {
  const int i = blockIdx.x * 256 + threadIdx.x;
  const int lane = i & 63;
  const int pkc  = i >> 6;
  const int cgrp = pkc & 1;
  const int ksg  = (pkc >> 1) & 255;
  const int p    = pkc >> 9;
  const int c  = cgrp * 32 + (lane & 31);
  const int k0 = ksg * 16 + (lane >> 5) * 8;
  const float* src = w + (size_t)p * 262144 + (size_t)c * 4096 + k0;
  const float4 v0 = *(const float4*)(src);
  const float4 v1 = *(const float4*)(src + 4);
  half8 h = { (_Float16)v0.x, (_Float16)v0.y, (_Float16)v0.z, (_Float16)v0.w,
              (_Float16)v1.x, (_Float16)v1.y, (_Float16)v1.z, (_Float16)v1.w };
  *(half8*)(o + (size_t)i * 8) = h;
}

// One-time transpose: X1T[s][a][z] and X2T[s][z][b], f16.
// s: 0 = L0; 1..3 = L1 spatial j; 4..12 = L2 spatial j.
__global__ __launch_bounds__(256) void xpose_kernel(
    const float* __restrict__ x1, const float* __restrict__ x2,
    _Float16* __restrict__ X1T, _Float16* __restrict__ X2T)
{
  __shared__ _Float16 T[64][66];
  const int s = blockIdx.y;
  const int which = blockIdx.z;      // 0: x1 -> X1T, 1: x2 -> X2T
  const int zbase = blockIdx.x * 64;
  int offs, d, j;
  if (s == 0)      { offs = 0;   d = 1; j = 0; }
  else if (s < 4)  { offs = 64;  d = 3; j = s - 1; }
  else             { offs = 256; d = 9; j = s - 4; }
  const float* __restrict__ src = which ? x2 : x1;
  const int tid = threadIdx.x;
  const int kk = tid & 63;
  const int z4 = tid >> 6;
  #pragma unroll
  for (int i = 0; i < 16; ++i) {
    const int zz = z4 + i * 4;
    T[kk][zz] = (_Float16)src[(size_t)(zbase + zz) * FEAT + offs + kk * d + j];
  }
  __syncthreads();
  const int c = tid & 63;
  const int r4 = tid >> 6;
  if (which == 0) {
    #pragma unroll
    for (int i = 0; i < 16; ++i) {
      const int a = r4 + i * 4;
      X1T[(size_t)(s * 64 + a) * 4096 + zbase + c] = T[a][c];   // z contiguous
    }
  } else {
    #pragma unroll
    for (int i = 0; i < 16; ++i) {
      const int zz = r4 + i * 4;
      X2T[((size_t)s * 4096 + zbase + zz) * 64 + c] = T[c][zz]; // b contiguous
    }
  }
}

__device__ __forceinline__ half8 splat8(_Float16 h) {
  return half8{h, h, h, h, h, h, h, h};
}

// Wave computes its (chunk, m): 2 c-group accs, 32 z, a in [a0, a0+32).
// x2 fragments: ds_read_b128 from X2L (a-invariant, kept in regs).
// x1 scalars: 1-line global u16 loads from X1T, 2-step prefetch, sign via XOR.
// W: single-buffered af, next-step loads issued after the MFMA cluster.
template<int NT>
__device__ __forceinline__ void run_chunk(
    const Chunk C, const int zbase, const int zl, const int hf,
    const int lane, const int a0,
    const _Float16* __restrict__ Wh, const unsigned short* __restrict__ X1u,
    const _Float16* __restrict__ X2L,
    floatx16& acc0, floatx16& acc1)
{
  half8 x2r[NT][4];
  #pragma unroll
  for (int t = 0; t < NT; ++t) {
    const _Float16* row = X2L + (C.s2[t] * 64 + zl) * 72 + hf * 8;
    #pragma unroll
    for (int ks = 0; ks < 4; ++ks)
      x2r[t][ks] = *(const half8*)(row + ks * 16);
  }

  const unsigned short* xp[NT];
  #pragma unroll
  for (int t = 0; t < NT; ++t)
    xp[t] = X1u + (size_t)(C.s1[t] * 64) * 4096 + zbase + zl;

  const _Float16* __restrict__ Wq = Wh + C.wbase + lane * 8;

  half8 af[2][4];
  {
    const _Float16* w0 = Wq + (size_t)a0 * 4096;
    #pragma unroll
    for (int ks = 0; ks < 4; ++ks) {
      af[0][ks] = *(const half8*)(w0 + ks * 1024);
      af[1][ks] = *(const half8*)(w0 + ks * 1024 + 512);
    }
  }
  unsigned short sc[NT], scn[NT];
  #pragma unroll
  for (int t = 0; t < NT; ++t) {
    sc[t]  = xp[t][(size_t)a0 * 4096];
    scn[t] = xp[t][(size_t)(a0 + 1) * 4096];
  }

  const int aend = a0 + 32;
  #pragma unroll 1
  for (int a = a0; a < aend; ++a) {
    half8 sv[NT];
    #pragma unroll
    for (int t = 0; t < NT; ++t) {
      unsigned short u = (unsigned short)(sc[t] ^ C.sgm[t]);  // exact +-
      _Float16 h;
      __builtin_memcpy(&h, &u, 2);
      sv[t] = splat8(h);
    }
    #pragma unroll
    for (int t = 0; t < NT; ++t) sc[t] = scn[t];
    if (a + 2 < aend) {
      #pragma unroll
      for (int t = 0; t < NT; ++t) scn[t] = xp[t][(size_t)(a + 2) * 4096];
    }
    __builtin_amdgcn_s_setprio(1);
    #pragma unroll
    for (int ks = 0; ks < 4; ++ks) {
      half8 tb = sv[0] * x2r[0][ks];
      if (NT > 1) tb += sv[1] * x2r[1][ks];
      if (NT > 2) tb += sv[2] * x2r[2][ks];
      acc0 = __builtin_amdgcn_mfma_f32_32x32x16_f16(af[0][ks], tb, acc0, 0, 0, 0);
      acc1 = __builtin_amdgcn_mfma_f32_32x32x16_f16(af[1][ks], tb, acc1, 0, 0, 0);
    }
    __builtin_amdgcn_s_setprio(0);
    if (a + 1 < aend) {   // next-step W loads AFTER the MFMAs that read af
      const _Float16* wn = Wq + (size_t)(a + 1) * 4096;
      #pragma unroll
      for (int ks = 0; ks < 4; ++ks) {
        af[0][ks] = *(const half8*)(wn + ks * 1024);
        af[1][ks] = *(const half8*)(wn + ks * 1024 + 512);
      }
    }
  }
}

__global__ __launch_bounds__(768) void tp_kernel(
    const _Float16* __restrict__ Wh, const unsigned short* __restrict__ X1u,
    const _Float16* __restrict__ X2Tg, float* __restrict__ out)
{
  __shared__ __align__(16) _Float16 X2L[13 * 64 * 72];  // 119,808 B
  __shared__ Chunk chs[3][7];
  __shared__ int nch_s;

  const int tid = threadIdx.x;
  const int bid = blockIdx.x;
  // bid<256: u=(bid&7)*32+(bid>>3) -> XCD-pair per slot-group (bid%8 -> XCD).
  int g, zt;
  if (bid < 256) { const int u = (bid & 7) * 32 + (bid >> 3); g = 1 + (u >> 6); zt = u & 63; }
  else           { g = 0; zt = bid - 256; }
  const int zbase = zt * 64;
  const int wid  = tid >> 6;            // 0..11
  const int zg   = wid & 1;
  const int aq   = (wid >> 1) & 1;
  const int mm   = wid >> 2;            // 0..2
  const int a0   = aq * 32;
  const int lane = tid & 63;
  const int ln31 = lane & 31;
  const int hf   = lane >> 5;
  const int zl   = zg * 32 + ln31;

  if (tid == 0) {
    auto plane = [](int L, int j) { return L == 0 ? 0 : (L == 1 ? 1 + j : 4 + j); };
    for (int m = 0; m < 3; ++m) {
      int n = 0;
      auto add = [&](int p, int L1, int L2, int i0,int i1,int i2,
                     int j0,int j1,int j2, float s0,float s1,float s2, int nt) {
        Chunk c;
        c.wbase = p * 262144;
        const int is[3] = {i0,i1,i2}, js[3] = {j0,j1,j2};
        const float ss[3] = {s0,s1,s2};
        for (int t = 0; t < 3; ++t) {
          c.s1[t] = plane(L1, is[t]);
          c.s2[t] = plane(L2, js[t]);
          c.sgm[t] = ss[t] < 0.f ? (unsigned short)0x8000 : (unsigned short)0;
        }
        c.nt = nt;
        chs[m][n++] = c;
      };
      if (g == 0) {
        if (m == 0) {
          add(0, 0,0, 0,0,0, 0,0,0, 1,0,0, 1);                  // A0*B0
          add(5, 1,1, 0,1,2, 0,1,2, 1,1,1, 3);                  // sum A1.B1
          add(13,2,2, 0,1,2, 0,1,2, 1,1,1, 3);                  // sum A2.B2 (x3)
          add(13,2,2, 3,4,5, 3,4,5, 1,1,1, 3);
          add(13,2,2, 6,7,8, 6,7,8, 1,1,1, 3);
          nch_s = n;
        }
      } else {
        const int slot = 3 * g - 2 + m;
        if (slot < 4) {
          const int mi = slot - 1, p1 = (mi+1)%3, p2 = (mi+2)%3;
          add(1, 0,1, 0,0,0, mi,0,0, 1,0,0, 1);
          add(3, 1,0, mi,0,0, 0,0,0, 1,0,0, 1);
          add(6, 1,1, p1,p2,0, p2,p1,0, 1,-1,0, 2);
          add(7, 1,2, 0,1,2, 3*mi,3*mi+1,3*mi+2, 1,1,1, 3);
          add(10,2,1, 3*mi,3*mi+1,3*mi+2, 0,1,2, 1,1,1, 3);
          add(14,2,2, 3*p1,3*p1+1,3*p1+2, 3*p2,3*p2+1,3*p2+2, 1,1,1, 3);
          add(14,2,2, 3*p2,3*p2+1,3*p2+2, 3*p1,3*p1+1,3*p1+2, -1,-1,-1, 3);
        } else {
          const int mi = slot - 4, uu = mi/3, v = mi%3, q1 = (v+1)%3, q2 = (v+2)%3;
          add(2, 0,2, 0,0,0, mi,0,0, 1,0,0, 1);
          add(4, 1,1, uu,0,0, v,0,0, 1,0,0, 1);
          add(8, 1,2, q1,q2,0, 3*uu+q2,3*uu+q1,0, 1,-1,0, 2);
          add(9, 2,0, mi,0,0, 0,0,0, 1,0,0, 1);
          add(11,2,1, 3*uu+q1,3*uu+q2,0, q2,q1,0, 1,-1,0, 2);
          add(12,2,2, 3*uu,3*uu+1,3*uu+2, 3*v,3*v+1,3*v+2, 1,1,1, 3);
        }
        nch_s = n;
      }
    }
  }

  // stage full x2 tile (13 planes) into LDS once, coalesced half8 copies
  for (int idx = tid; idx < 13 * 64 * 8; idx += 768) {
    const int s  = idx >> 9;
    const int rem = idx & 511;
    const int zz = rem >> 3;
    const int o8 = rem & 7;
    *(half8*)(X2L + (s * 64 + zz) * 72 + o8 * 8) =
        *(const half8*)(X2Tg + ((size_t)s * 4096 + zbase + zz) * 64 + o8 * 8);
  }
  __syncthreads();   // the ONLY barrier before the epilogue
  const int nch = nch_s;

  floatx16 acc0, acc1;
  #pragma unroll
  for (int r = 0; r < 16; ++r) { acc0[r] = 0.0f; acc1[r] = 0.0f; }

  if (g == 0) {
    // chunk-subset per m-wave: mm0 {0,3}, mm1 {1,4}, mm2 {2}
    for (int ci = mm; ci < nch; ci += 3) {
      const Chunk C = chs[0][ci];
      if (C.nt == 1)      run_chunk<1>(C, zbase, zl, hf, lane, a0, Wh, X1u, X2L, acc0, acc1);
      else if (C.nt == 2) run_chunk<2>(C, zbase, zl, hf, lane, a0, Wh, X1u, X2L, acc0, acc1);
      else                run_chunk<3>(C, zbase, zl, hf, lane, a0, Wh, X1u, X2L, acc0, acc1);
    }
  } else {
    for (int ci = 0; ci < nch; ++ci) {
      const Chunk C = chs[mm][ci];
      if (C.nt == 1)      run_chunk<1>(C, zbase, zl, hf, lane, a0, Wh, X1u, X2L, acc0, acc1);
      else if (C.nt == 2) run_chunk<2>(C, zbase, zl, hf, lane, a0, Wh, X1u, X2L, acc0, acc1);
      else                run_chunk<3>(C, zbase, zl, hf, lane, a0, Wh, X1u, X2L, acc0, acc1);
    }
  }

  // reduction: Dv aliases X2L. Non-writer waves dump; writers add + store.
  __syncthreads();
  float* __restrict__ Dv = (float*)X2L;
  const bool writer = (aq == 0) && (g > 0 || mm == 0);
  if (!writer) {
    const int b = ((mm * 2 + aq) * 2 + zg) * 2048;
    #pragma unroll
    for (int r = 0; r < 16; ++r) {
      Dv[b + r * 64 + lane]        = acc0[r];
      Dv[b + 1024 + r * 64 + lane] = acc1[r];
    }
  }
  __syncthreads();
  if (writer) {
    if (g > 0) {
      const int b = ((mm * 2 + 1) * 2 + zg) * 2048;   // aq=1 partner
      #pragma unroll
      for (int r = 0; r < 16; ++r) {
        acc0[r] += Dv[b + r * 64 + lane];
        acc1[r] += Dv[b + 1024 + r * 64 + lane];
      }
    } else {
      #pragma unroll
      for (int m2 = 0; m2 < 3; ++m2) {
        #pragma unroll
        for (int q2 = 0; q2 < 2; ++q2) {
          if (m2 == 0 && q2 == 0) continue;
          const int b = ((m2 * 2 + q2) * 2 + zg) * 2048;
          #pragma unroll
          for (int r = 0; r < 16; ++r) {
            acc0[r] += Dv[b + r * 64 + lane];
            acc1[r] += Dv[b + 1024 + r * 64 + lane];
          }
        }
      }
    }
    const int slot = (g == 0) ? 0 : 3 * g - 2 + mm;
    int offO, dO, mO;
    if (slot == 0)      { offO = 0;   dO = 1; mO = 0; }
    else if (slot < 4)  { offO = 64;  dO = 3; mO = slot - 1; }
    else                { offO = 256; dO = 9; mO = slot - 4; }
    // C/D 32x32 layout: col(z)=lane&31, row(c)=(r&3)+8*(r>>2)+4*hf
    float* __restrict__ op = out + (size_t)(zbase + zl) * FEAT + offO + mO;
    #pragma unroll
    for (int r = 0; r < 16; ++r) {
      const int cr = (r & 3) + 8 * (r >> 2) + 4 * hf;
      op[(size_t)cr * dO]        = acc0[r];
      op[(size_t)(cr + 32) * dO] = acc1[r];
    }
  }
}

extern "C" void kernel_launch(void* const* d_in, const int* in_sizes, int n_in,
                              void* d_out, int out_size, void* d_ws, size_t ws_size,
                              hipStream_t stream) {
  const float* x1 = (const float*)d_in[0];
  const float* x2 = (const float*)d_in[1];
  const float* w  = (const float*)d_in[2];
  float* out = (float*)d_out;
  _Float16* Wh  = (_Float16*)d_ws;                                 // 7,864,320 B
  _Float16* X1T = (_Float16*)((char*)d_ws + 7864320);              // 6,815,744 B
  _Float16* X2T = (_Float16*)((char*)d_ws + 7864320 + 6815744);    // 6,815,744 B

  const int nchunks = 15 * 64 * 4096 / 8;    // 491520 half8 chunks
  hipLaunchKernelGGL(swz_w_kernel, dim3(nchunks / 256), dim3(256), 0, stream, w, Wh);
  hipLaunchKernelGGL(xpose_kernel, dim3(64, 13, 2), dim3(256), 0, stream,
                     x1, x2, X1T, X2T);
  // 256 slot-group blocks (g1..g4, XCD-paired) + 64 slot-0 tail blocks
  hipLaunchKernelGGL(tp_kernel, dim3(320), dim3(768), 0, stream,
                     Wh, (const unsigned short*)X1T, X2T, out);
}

// Round 10
// 450.395 us; speedup vs baseline: 1.0305x; 1.0305x over previous
//
#include <hip/hip_runtime.h>
#include <cstdint>
#include <cstddef>

// PureCartesianTensorProduct: B=4096, C1=C2=COUT=64, LMAX=2, FEAT=832, 15 paths.
// out[z,c,m] = sum_p sum_ab W_p[c,a,b] * T_p,m[z,a,b].   MFMA f32_32x32x16_f16.
//
// R10 = R9 structure with the register budget fixed and the wave shape
// rebalanced. R9 post-mortem: __launch_bounds__(768) w/o min-waves let the
// compiler cap VGPR at 84 -> ~150-reg working set spilled (WRITE 133 MB).
// Fixes:
//  * __launch_bounds__(768, 3): 3 waves/EU = 1 block/CU -> reg cap 170.
//  * Wave = (zg 2) x (cg 2) x (m 3): ONE c-group per wave (acc 16 regs) so
//    the PROVEN 2-deep even/odd W prefetch fits (32 regs, full-a-step L2
//    latency cover; R9's single-buffer af stalled every step). Hard regs:
//    x2r 48 + af 32 + acc 16 + misc ~50 = ~145 < 170.
//  * Each wave owns a disjoint (slot, cg, zg) output block -> ZERO epilogue
//    reduction for the 256 main blocks; g0 tail keeps a 3-way LDS reduce.
// Carried from R9 (all verified passing):
//  * Slot-triples share W (L1/L2 dedup; XCD-grouped grid -> ~3MB L2-resident
//    W set per XCD). FETCH dropped to 73 MB in R9 -- scatter is gone.
//  * One-time transpose pre-kernel: X1T[s][a][z] (1-line x1 scalar loads,
//    2-step prefetch), X2T[s][z][b] -> LDS X2L[13][64][72] staged once,
//    clean ds_read_b128 fragments, zero bank conflicts.
//  * ZERO per-chunk barriers: one staging barrier, then waves free-run.
// Accepted cost: 320 blocks / 256 CUs = 2-round tail (~1.3x over 69us floor).

#define FEAT 832

typedef _Float16 half8 __attribute__((ext_vector_type(8)));
typedef float floatx16 __attribute__((ext_vector_type(16)));

struct Chunk {
  int wbase;               // p * 262144 into swizzled f16 W
  int s1[3];               // x1 plane index per term
  int s2[3];               // x2 plane index per term
  unsigned short sgm[3];   // f16 sign mask (0 or 0x8000)
  int nt;
};

// Swizzle W f32 [p][c][k] -> f16 A-frag order (unchanged, proven):
// Wsw[((p*256+ksg)*2+cgrp)*512 + lane*8+j] = W_p[cgrp*32+(lane&31)][ksg*16+(lane>>5)*8+j]
__global__ void swz_w_kernel(const float* __restrict__ w, _Float16* __restrict__ o) {
  const int i = blockIdx.x * 256 + threadIdx.x;
  const int lane = i & 63;
  const int pkc  = i >> 6;
  const int cgrp = pkc & 1;
  const int ksg  = (pkc >> 1) & 255;
  const int p    = pkc >> 9;
  const int c  = cgrp * 32 + (lane & 31);
  const int k0 = ksg * 16 + (lane >> 5) * 8;
  const float* src = w + (size_t)p * 262144 + (size_t)c * 4096 + k0;
  const float4 v0 = *(const float4*)(src);
  const float4 v1 = *(const float4*)(src + 4);
  half8 h = { (_Float16)v0.x, (_Float16)v0.y, (_Float16)v0.z, (_Float16)v0.w,
              (_Float16)v1.x, (_Float16)v1.y, (_Float16)v1.z, (_Float16)v1.w };
  *(half8*)(o + (size_t)i * 8) = h;
}

// One-time transpose: X1T[s][a][z] and X2T[s][z][b], f16.
// s: 0 = L0; 1..3 = L1 spatial j; 4..12 = L2 spatial j.
__global__ __launch_bounds__(256) void xpose_kernel(
    const float* __restrict__ x1, const float* __restrict__ x2,
    _Float16* __restrict__ X1T, _Float16* __restrict__ X2T)
{
  __shared__ _Float16 T[64][66];
  const int s = blockIdx.y;
  const int which = blockIdx.z;      // 0: x1 -> X1T, 1: x2 -> X2T
  const int zbase = blockIdx.x * 64;
  int offs, d, j;
  if (s == 0)      { offs = 0;   d = 1; j = 0; }
  else if (s < 4)  { offs = 64;  d = 3; j = s - 1; }
  else             { offs = 256; d = 9; j = s - 4; }
  const float* __restrict__ src = which ? x2 : x1;
  const int tid = threadIdx.x;
  const int kk = tid & 63;
  const int z4 = tid >> 6;
  #pragma unroll
  for (int i = 0; i < 16; ++i) {
    const int zz = z4 + i * 4;
    T[kk][zz] = (_Float16)src[(size_t)(zbase + zz) * FEAT + offs + kk * d + j];
  }
  __syncthreads();
  const int c = tid & 63;
  const int r4 = tid >> 6;
  if (which == 0) {
    #pragma unroll
    for (int i = 0; i < 16; ++i) {
      const int a = r4 + i * 4;
      X1T[(size_t)(s * 64 + a) * 4096 + zbase + c] = T[a][c];   // z contiguous
    }
  } else {
    #pragma unroll
    for (int i = 0; i < 16; ++i) {
      const int zz = r4 + i * 4;
      X2T[((size_t)s * 4096 + zbase + zz) * 64 + c] = T[c][zz]; // b contiguous
    }
  }
}

__device__ __forceinline__ half8 splat8(_Float16 h) {
  return half8{h, h, h, h, h, h, h, h};
}

// Wave computes (chunk, its c-group): one 32c x 32z acc, full a = 0..63.
// x2 fragments: ds_read_b128 from X2L (a-invariant, kept in regs).
// x1 scalars: 1-line global u16 loads from X1T, 2-step prefetch, sign via XOR.
// W: 2-deep even/odd prefetch (full a-step latency cover), this cg only.
template<int NT>
__device__ __forceinline__ void run_chunk(
    const Chunk C, const int zbase, const int zl, const int hf,
    const int lane, const int cg,
    const _Float16* __restrict__ Wh, const unsigned short* __restrict__ X1u,
    const _Float16* __restrict__ X2L,
    floatx16& acc)
{
  half8 x2r[NT][4];
  #pragma unroll
  for (int t = 0; t < NT; ++t) {
    const _Float16* row = X2L + (C.s2[t] * 64 + zl) * 72 + hf * 8;
    #pragma unroll
    for (int ks = 0; ks < 4; ++ks)
      x2r[t][ks] = *(const half8*)(row + ks * 16);
  }

  const unsigned short* xp[NT];
  #pragma unroll
  for (int t = 0; t < NT; ++t)
    xp[t] = X1u + (size_t)(C.s1[t] * 64) * 4096 + zbase + zl;

  const _Float16* __restrict__ Wq = Wh + C.wbase + cg * 512 + lane * 8;

  // 2-deep W prefetch: even/odd a buffers (this wave's c-group slice)
  half8 afE[4], afO[4];
  #pragma unroll
  for (int ks = 0; ks < 4; ++ks) {
    afE[ks] = *(const half8*)(Wq + ks * 1024);
    afO[ks] = *(const half8*)(Wq + 4096 + ks * 1024);
  }
  unsigned short sc[NT], scn[NT];
  #pragma unroll
  for (int t = 0; t < NT; ++t) {
    sc[t]  = xp[t][0];
    scn[t] = xp[t][4096];
  }

  #pragma unroll 1
  for (int a = 0; a < 64; a += 2) {
    {  // even: compute a, prefetch a+2
      half8 sv[NT];
      #pragma unroll
      for (int t = 0; t < NT; ++t) {
        unsigned short u = (unsigned short)(sc[t] ^ C.sgm[t]);
        _Float16 h; __builtin_memcpy(&h, &u, 2);
        sv[t] = splat8(h);
      }
      if (a + 2 < 64) {
        #pragma unroll
        for (int t = 0; t < NT; ++t) sc[t] = xp[t][(size_t)(a + 2) * 4096];
      }
      __builtin_amdgcn_s_setprio(1);
      #pragma unroll
      for (int ks = 0; ks < 4; ++ks) {
        half8 tb = sv[0] * x2r[0][ks];
        if (NT > 1) tb += sv[1] * x2r[1][ks];
        if (NT > 2) tb += sv[2] * x2r[2][ks];
        acc = __builtin_amdgcn_mfma_f32_32x32x16_f16(afE[ks], tb, acc, 0, 0, 0);
      }
      __builtin_amdgcn_s_setprio(0);
      if (a + 2 < 64) {
        const _Float16* wn = Wq + (size_t)(a + 2) * 4096;
        #pragma unroll
        for (int ks = 0; ks < 4; ++ks)
          afE[ks] = *(const half8*)(wn + ks * 1024);
      }
    }
    {  // odd: compute a+1, prefetch a+3
      half8 sv[NT];
      #pragma unroll
      for (int t = 0; t < NT; ++t) {
        unsigned short u = (unsigned short)(scn[t] ^ C.sgm[t]);
        _Float16 h; __builtin_memcpy(&h, &u, 2);
        sv[t] = splat8(h);
      }
      if (a + 3 < 64) {
        #pragma unroll
        for (int t = 0; t < NT; ++t) scn[t] = xp[t][(size_t)(a + 3) * 4096];
      }
      __builtin_amdgcn_s_setprio(1);
      #pragma unroll
      for (int ks = 0; ks < 4; ++ks) {
        half8 tb = sv[0] * x2r[0][ks];
        if (NT > 1) tb += sv[1] * x2r[1][ks];
        if (NT > 2) tb += sv[2] * x2r[2][ks];
        acc = __builtin_amdgcn_mfma_f32_32x32x16_f16(afO[ks], tb, acc, 0, 0, 0);
      }
      __builtin_amdgcn_s_setprio(0);
      if (a + 3 < 64) {
        const _Float16* wn = Wq + (size_t)(a + 3) * 4096;
        #pragma unroll
        for (int ks = 0; ks < 4; ++ks)
          afO[ks] = *(const half8*)(wn + ks * 1024);
      }
    }
  }
}

__global__ __launch_bounds__(768, 3) void tp_kernel(
    const _Float16* __restrict__ Wh, const unsigned short* __restrict__ X1u,
    const _Float16* __restrict__ X2Tg, float* __restrict__ out)
{
  __shared__ __align__(16) _Float16 X2L[13 * 64 * 72];  // 119,808 B
  __shared__ Chunk chs[3][7];
  __shared__ int nch_s;

  const int tid = threadIdx.x;
  const int bid = blockIdx.x;
  // bid<256: u=(bid&7)*32+(bid>>3) -> XCD-grouped slot-triples (bid%8 -> XCD).
  int g, zt;
  if (bid < 256) { const int u = (bid & 7) * 32 + (bid >> 3); g = 1 + (u >> 6); zt = u & 63; }
  else           { g = 0; zt = bid - 256; }
  const int zbase = zt * 64;
  const int wid  = tid >> 6;            // 0..11
  const int zg   = wid & 1;
  const int cg   = (wid >> 1) & 1;      // c-group: rows cg*32..cg*32+31
  const int mm   = wid >> 2;            // 0..2 (m-wave / slot within triple)
  const int lane = tid & 63;
  const int ln31 = lane & 31;
  const int hf   = lane >> 5;
  const int zl   = zg * 32 + ln31;

  if (tid == 0) {
    auto plane = [](int L, int j) { return L == 0 ? 0 : (L == 1 ? 1 + j : 4 + j); };
    for (int m = 0; m < 3; ++m) {
      int n = 0;
      auto add = [&](int p, int L1, int L2, int i0,int i1,int i2,
                     int j0,int j1,int j2, float s0,float s1,float s2, int nt) {
        Chunk c;
        c.wbase = p * 262144;
        const int is[3] = {i0,i1,i2}, js[3] = {j0,j1,j2};
        const float ss[3] = {s0,s1,s2};
        for (int t = 0; t < 3; ++t) {
          c.s1[t] = plane(L1, is[t]);
          c.s2[t] = plane(L2, js[t]);
          c.sgm[t] = ss[t] < 0.f ? (unsigned short)0x8000 : (unsigned short)0;
        }
        c.nt = nt;
        chs[m][n++] = c;
      };
      if (g == 0) {
        if (m == 0) {
          add(0, 0,0, 0,0,0, 0,0,0, 1,0,0, 1);                  // A0*B0
          add(5, 1,1, 0,1,2, 0,1,2, 1,1,1, 3);                  // sum A1.B1
          add(13,2,2, 0,1,2, 0,1,2, 1,1,1, 3);                  // sum A2.B2 (x3)
          add(13,2,2, 3,4,5, 3,4,5, 1,1,1, 3);
          add(13,2,2, 6,7,8, 6,7,8, 1,1,1, 3);
          nch_s = n;
        }
      } else {
        const int slot = 3 * g - 2 + m;
        if (slot < 4) {
          const int mi = slot - 1, p1 = (mi+1)%3, p2 = (mi+2)%3;
          add(1, 0,1, 0,0,0, mi,0,0, 1,0,0, 1);
          add(3, 1,0, mi,0,0, 0,0,0, 1,0,0, 1);
          add(6, 1,1, p1,p2,0, p2,p1,0, 1,-1,0, 2);
          add(7, 1,2, 0,1,2, 3*mi,3*mi+1,3*mi+2, 1,1,1, 3);
          add(10,2,1, 3*mi,3*mi+1,3*mi+2, 0,1,2, 1,1,1, 3);
          add(14,2,2, 3*p1,3*p1+1,3*p1+2, 3*p2,3*p2+1,3*p2+2, 1,1,1, 3);
          add(14,2,2, 3*p2,3*p2+1,3*p2+2, 3*p1,3*p1+1,3*p1+2, -1,-1,-1, 3);
        } else {
          const int mi = slot - 4, uu = mi/3, v = mi%3, q1 = (v+1)%3, q2 = (v+2)%3;
          add(2, 0,2, 0,0,0, mi,0,0, 1,0,0, 1);
          add(4, 1,1, uu,0,0, v,0,0, 1,0,0, 1);
          add(8, 1,2, q1,q2,0, 3*uu+q2,3*uu+q1,0, 1,-1,0, 2);
          add(9, 2,0, mi,0,0, 0,0,0, 1,0,0, 1);
          add(11,2,1, 3*uu+q1,3*uu+q2,0, q2,q1,0, 1,-1,0, 2);
          add(12,2,2, 3*uu,3*uu+1,3*uu+2, 3*v,3*v+1,3*v+2, 1,1,1, 3);
        }
        nch_s = n;
      }
    }
  }

  // stage full x2 tile (13 planes) into LDS once, coalesced half8 copies
  for (int idx = tid; idx < 13 * 64 * 8; idx += 768) {
    const int s  = idx >> 9;
    const int rem = idx & 511;
    const int zz = rem >> 3;
    const int o8 = rem & 7;
    *(half8*)(X2L + (s * 64 + zz) * 72 + o8 * 8) =
        *(const half8*)(X2Tg + ((size_t)s * 4096 + zbase + zz) * 64 + o8 * 8);
  }
  __syncthreads();   // the ONLY barrier for g>0 blocks
  const int nch = nch_s;

  floatx16 acc;
  #pragma unroll
  for (int r = 0; r < 16; ++r) acc[r] = 0.0f;

  if (g == 0) {
    // chunk-subset per m-wave: mm0 {0,3}, mm1 {1,4}, mm2 {2}
    for (int ci = mm; ci < nch; ci += 3) {
      const Chunk C = chs[0][ci];
      if (C.nt == 1)      run_chunk<1>(C, zbase, zl, hf, lane, cg, Wh, X1u, X2L, acc);
      else if (C.nt == 2) run_chunk<2>(C, zbase, zl, hf, lane, cg, Wh, X1u, X2L, acc);
      else                run_chunk<3>(C, zbase, zl, hf, lane, cg, Wh, X1u, X2L, acc);
    }
  } else {
    for (int ci = 0; ci < nch; ++ci) {
      const Chunk C = chs[mm][ci];
      if (C.nt == 1)      run_chunk<1>(C, zbase, zl, hf, lane, cg, Wh, X1u, X2L, acc);
      else if (C.nt == 2) run_chunk<2>(C, zbase, zl, hf, lane, cg, Wh, X1u, X2L, acc);
      else                run_chunk<3>(C, zbase, zl, hf, lane, cg, Wh, X1u, X2L, acc);
    }
  }

  if (g > 0) {
    // direct write: wave owns (slot = 3g-2+mm, cg, zg) -- disjoint, no races.
    const int slot = 3 * g - 2 + mm;
    int offO, dO, mO;
    if (slot < 4) { offO = 64;  dO = 3; mO = slot - 1; }
    else          { offO = 256; dO = 9; mO = slot - 4; }
    float* __restrict__ op = out + (size_t)(zbase + zl) * FEAT + offO + mO;
    #pragma unroll
    for (int r = 0; r < 16; ++r) {
      const int cr = cg * 32 + (r & 3) + 8 * (r >> 2) + 4 * hf;
      op[(size_t)cr * dO] = acc[r];
    }
  } else {
    // g0: 3-way reduction over m-waves per (cg, zg), then slot-0 write.
    __syncthreads();
    float* __restrict__ Dv = (float*)X2L;
    if (mm > 0) {
      const int b = (((mm - 1) * 2 + cg) * 2 + zg) * 1024;
      #pragma unroll
      for (int r = 0; r < 16; ++r)
        Dv[b + r * 64 + lane] = acc[r];
    }
    __syncthreads();
    if (mm == 0) {
      #pragma unroll
      for (int m2 = 1; m2 < 3; ++m2) {
        const int b = (((m2 - 1) * 2 + cg) * 2 + zg) * 1024;
        #pragma unroll
        for (int r = 0; r < 16; ++r)
          acc[r] += Dv[b + r * 64 + lane];
      }
      float* __restrict__ op = out + (size_t)(zbase + zl) * FEAT;  // slot 0
      #pragma unroll
      for (int r = 0; r < 16; ++r) {
        const int cr = cg * 32 + (r & 3) + 8 * (r >> 2) + 4 * hf;
        op[cr] = acc[r];
      }
    }
  }
}

extern "C" void kernel_launch(void* const* d_in, const int* in_sizes, int n_in,
                              void* d_out, int out_size, void* d_ws, size_t ws_size,
                              hipStream_t stream) {
  const float* x1 = (const float*)d_in[0];
  const float* x2 = (const float*)d_in[1];
  const float* w  = (const float*)d_in[2];
  float* out = (float*)d_out;
  _Float16* Wh  = (_Float16*)d_ws;                                 // 7,864,320 B
  _Float16* X1T = (_Float16*)((char*)d_ws + 7864320);              // 6,815,744 B
  _Float16* X2T = (_Float16*)((char*)d_ws + 7864320 + 6815744);    // 6,815,744 B

  const int nchunks = 15 * 64 * 4096 / 8;    // 491520 half8 chunks
  hipLaunchKernelGGL(swz_w_kernel, dim3(nchunks / 256), dim3(256), 0, stream, w, Wh);
  hipLaunchKernelGGL(xpose_kernel, dim3(64, 13, 2), dim3(256), 0, stream,
                     x1, x2, X1T, X2T);
  // 256 slot-group blocks (g1..g4, XCD-grouped) + 64 slot-0 tail blocks
  hipLaunchKernelGGL(tp_kernel, dim3(320), dim3(768), 0, stream,
                     Wh, (const unsigned short*)X1T, X2T, out);
}